// Round 4
// baseline (421.699 us; speedup 1.0000x reference)
//
#include <hip/hip_runtime.h>
#include <hip/hip_bf16.h>

// FieldDecoder: B=16, 64x64 tokens, DO=768, kernel 16x16, stride 8, field 512x512
#define DIM      768
#define NPATCH   4096
#define BATCH    16
#define MROWS    65536
#define NCOLS    256

typedef __attribute__((ext_vector_type(8))) short bf16x8;
typedef __attribute__((ext_vector_type(4))) float f32x4;

static __device__ __forceinline__ unsigned short f2bf(float f) {
    union { float f; unsigned int u; } v; v.f = f;
    unsigned int u = v.u;
    return (unsigned short)((u + 0x7FFFu + ((u >> 16) & 1u)) >> 16);
}
static __device__ __forceinline__ float bf2f(unsigned int u16) {
    union { unsigned int i; float f; } x; x.i = u16 << 16; return x.f;
}

// ---------------- kernel 0: weight fp32 -> bf16 ----------------
__global__ void wconv_kernel(const float* __restrict__ w, unsigned short* __restrict__ wb) {
    int i = blockIdx.x * blockDim.x + threadIdx.x;
    float4 v = ((const float4*)w)[i];
    unsigned int p0 = (unsigned)f2bf(v.x) | ((unsigned)f2bf(v.y) << 16);
    unsigned int p1 = (unsigned)f2bf(v.z) | ((unsigned)f2bf(v.w) << 16);
    ((uint2*)wb)[i] = make_uint2(p0, p1);
}

// ---------------- kernel 1: slim GEMM  proj[M,256] = A[M,768](fp32->bf16) x Bw[256,768]^T --------
// M=32 per block (2048 blocks, ~8/CU dispatched), 4 waves n-split (wave -> 64 cols).
// A staged in 16 KB LDS per 128-k chunk (small bursts, 6 chunks); B global-direct (L2-resident).
// MFMA 16x16x32 with R3-verified fragment & C/D layouts.
#define CHUNK 128
#define LSTC  136     // staging row stride (shorts); 272 B keeps ds_read_b128 16B-aligned

__global__ __launch_bounds__(256, 6) void gemm_kernel(const float* __restrict__ A,
                                                      const unsigned short* __restrict__ Bw,
                                                      unsigned short* __restrict__ Cb) {
    __shared__ unsigned short smem[32 * 256];   // 16 KB: staging uses 32*136, epilogue 32*256

    const int tid  = threadIdx.x;
    const int m0   = blockIdx.x * 32;
    const int wv   = tid >> 6;          // wave -> cols wv*64 .. +63
    const int lane = tid & 63;
    const int l15  = lane & 15;
    const int quad = lane >> 4;

    f32x4 acc[2][4] = {};

    const unsigned short* bBase[4];
    #pragma unroll
    for (int j = 0; j < 4; ++j)
        bBase[j] = Bw + (size_t)(wv * 64 + j * 16 + l15) * DIM + quad * 8;
    const unsigned short* aFrag0 = smem + l15 * LSTC + quad * 8;
    const unsigned short* aFrag1 = aFrag0 + 16 * LSTC;

    const int srow = tid >> 3;          // 0..31
    const int su   = tid & 7;
    const float* aSrc = A + (size_t)(m0 + srow) * DIM + su * 4;
    unsigned short* aDst = smem + srow * LSTC + su * 4;

    for (int c = 0; c < 6; ++c) {
        const int kb = c * CHUNK;
        __syncthreads();                 // previous chunk's ds_reads done
        #pragma unroll
        for (int p = 0; p < 4; ++p) {    // 16 KB burst: 4 x float4 per thread
            float4 v = *(const float4*)(aSrc + kb + p * 32);
            unsigned int p0 = (unsigned)f2bf(v.x) | ((unsigned)f2bf(v.y) << 16);
            unsigned int p1 = (unsigned)f2bf(v.z) | ((unsigned)f2bf(v.w) << 16);
            *(uint2*)(aDst + p * 32) = make_uint2(p0, p1);
        }
        __syncthreads();
        #pragma unroll
        for (int kk = 0; kk < 4; ++kk) { // K=32 per step
            bf16x8 bf[4];
            #pragma unroll
            for (int j = 0; j < 4; ++j)
                bf[j] = *(const bf16x8*)(bBase[j] + kb + kk * 32);
            bf16x8 a0 = *(const bf16x8*)(aFrag0 + kk * 32);
            bf16x8 a1 = *(const bf16x8*)(aFrag1 + kk * 32);
            #pragma unroll
            for (int j = 0; j < 4; ++j) {
                acc[0][j] = __builtin_amdgcn_mfma_f32_16x16x32_bf16(a0, bf[j], acc[0][j], 0, 0, 0);
                acc[1][j] = __builtin_amdgcn_mfma_f32_16x16x32_bf16(a1, bf[j], acc[1][j], 0, 0, 0);
            }
        }
    }

    // epilogue: transpose through LDS -> 512 B/row coalesced bf16 stores
    __syncthreads();
    #pragma unroll
    for (int i = 0; i < 2; ++i)
        #pragma unroll
        for (int j = 0; j < 4; ++j)
            #pragma unroll
            for (int rr = 0; rr < 4; ++rr)
                smem[(i * 16 + quad * 4 + rr) * 256 + wv * 64 + j * 16 + l15] = f2bf(acc[i][j][rr]);
    __syncthreads();

    const int orow = tid >> 3;
    const int ou   = tid & 7;
    #pragma unroll
    for (int q = 0; q < 4; ++q) {
        uint4 v = *(const uint4*)(smem + orow * 256 + ou * 32 + q * 8);
        *(uint4*)(Cb + (size_t)(m0 + orow) * NCOLS + ou * 32 + q * 8) = v;
    }
}

// ---------------- kernel 2: gather-mean, block per (batch, patch-row h) ----------------
// LDS: full cur row (32 KB) + dh 8..15 half of prev row (16 KB) = 48 KB -> 3 blocks/CU.
__global__ __launch_bounds__(256) void gather_kernel(const unsigned short* __restrict__ proj,
                                                     float* __restrict__ out) {
    __shared__ unsigned short sCur[64 * 256];
    __shared__ unsigned short sPrevHi[64 * 128];

    const int blk = blockIdx.x;          // b*64 + h
    const int b   = blk >> 6;
    const int h   = blk & 63;
    const int tid = threadIdx.x;
    const unsigned short* base = proj + (size_t)b * (NPATCH * NCOLS);

    const uint4* gCur = (const uint4*)(base + (size_t)h * 64 * 256);
    #pragma unroll
    for (int p = 0; p < 8; ++p)
        ((uint4*)sCur)[tid + p * 256] = gCur[tid + p * 256];
    if (h > 0) {
        const uint4* gPrev = (const uint4*)(base + (size_t)(h - 1) * 64 * 256);
        #pragma unroll
        for (int p = 0; p < 4; ++p) {
            int i = tid + p * 256;       // patch = i>>4, 16B-unit = i&15 of hi half
            ((uint4*)sPrevHi)[i] = gPrev[(i >> 4) * 32 + 16 + (i & 15)];
        }
    }
    __syncthreads();

    const int r  = tid >> 5;             // output row in block: ph = 8h + r
    const int cg = tid & 31;             // 16 pixels: pw = cg*16 .. +15
    const int ph = h * 8 + r;
    const float inv_ch = (h == 0) ? 1.f : ((ph == 511) ? 0.1f : 0.5f);

    float res[16];
    #pragma unroll
    for (int j = 0; j < 16; ++j) {
        const int pw = cg * 16 + j;
        const int w1 = pw >> 3, dw = pw & 7;
        float v = bf2f(sCur[w1 * 256 + r * 16 + dw]);
        if (pw >= 8) v += bf2f(sCur[(w1 - 1) * 256 + r * 16 + dw + 8]);
        if (h > 0) {
            v += bf2f(sPrevHi[w1 * 128 + r * 16 + dw]);
            if (pw >= 8) v += bf2f(sPrevHi[(w1 - 1) * 128 + r * 16 + dw + 8]);
        }
        if (pw == 511) {                 // w-clamp extras: dw 8..15 of patch 63
            #pragma unroll
            for (int dwe = 8; dwe < 16; ++dwe) {
                v += bf2f(sCur[63 * 256 + r * 16 + dwe]);
                if (h > 0) v += bf2f(sPrevHi[63 * 128 + r * 16 + dwe]);
            }
        }
        if (ph == 511) {                 // h-clamp extras: dh 8..15 of cur row 63
            #pragma unroll 1
            for (int dh = 8; dh < 16; ++dh) {
                float e = bf2f(sCur[w1 * 256 + dh * 16 + dw]);
                if (pw >= 8) e += bf2f(sCur[(w1 - 1) * 256 + dh * 16 + dw + 8]);
                if (pw == 511) {
                    #pragma unroll
                    for (int dwe = 8; dwe < 16; ++dwe)
                        e += bf2f(sCur[63 * 256 + dh * 16 + dwe]);
                }
                v += e;
            }
        }
        const float inv_cw = (pw < 8) ? 1.f : ((pw == 511) ? 0.1f : 0.5f);
        res[j] = v * inv_ch * inv_cw;
    }

    float* orow = out + ((size_t)(b * 512 + ph)) * 512 + cg * 16;
    #pragma unroll
    for (int q = 0; q < 4; ++q)
        *(float4*)(orow + q * 4) = make_float4(res[4 * q], res[4 * q + 1], res[4 * q + 2], res[4 * q + 3]);
}

extern "C" void kernel_launch(void* const* d_in, const int* in_sizes, int n_in,
                              void* d_out, int out_size, void* d_ws, size_t ws_size,
                              hipStream_t stream) {
    const float* tgt    = (const float*)d_in[0];   // [16,4096,768] fp32
    const float* weight = (const float*)d_in[1];   // [16,16,768]  fp32
    float* out = (float*)d_out;                    // [16,512,512] fp32

    unsigned short* proj = (unsigned short*)d_ws;                                      // 32 MB bf16
    unsigned short* wbf  = (unsigned short*)((char*)d_ws + (size_t)MROWS * NCOLS * 2); // +384 KB

    wconv_kernel<<<192, 256, 0, stream>>>(weight, wbf);
    gemm_kernel<<<MROWS / 32, 256, 0, stream>>>(tgt, wbf, proj);   // 2048 blocks
    gather_kernel<<<BATCH * 64, 256, 0, stream>>>(proj, out);      // 1024 blocks
}

// Round 5
// 372.130 us; speedup vs baseline: 1.1332x; 1.1332x over previous
//
#include <hip/hip_runtime.h>
#include <hip/hip_bf16.h>

// FieldDecoder: B=16, 64x64 tokens, DO=768, kernel 16x16, stride 8, field 512x512
#define DIM      768
#define NPATCH   4096
#define BATCH    16
#define MROWS    65536
#define NCOLS    256

typedef __attribute__((ext_vector_type(8))) short bf16x8;
typedef __attribute__((ext_vector_type(4))) float f32x4;

static __device__ __forceinline__ unsigned short f2bf(float f) {
    union { float f; unsigned int u; } v; v.f = f;
    unsigned int u = v.u;
    return (unsigned short)((u + 0x7FFFu + ((u >> 16) & 1u)) >> 16);
}
static __device__ __forceinline__ float bf2f(unsigned int u16) {
    union { unsigned int i; float f; } x; x.i = u16 << 16; return x.f;
}
static __device__ __forceinline__ bf16x8 pack_bf8(float4 a, float4 b) {
    union { bf16x8 v; unsigned int u[4]; } r;
    r.u[0] = (unsigned)f2bf(a.x) | ((unsigned)f2bf(a.y) << 16);
    r.u[1] = (unsigned)f2bf(a.z) | ((unsigned)f2bf(a.w) << 16);
    r.u[2] = (unsigned)f2bf(b.x) | ((unsigned)f2bf(b.y) << 16);
    r.u[3] = (unsigned)f2bf(b.z) | ((unsigned)f2bf(b.w) << 16);
    return r.v;
}

// ---------------- kernel 0: pack W into MFMA B-fragment order ----------------
// Bfrag[((kk*16 + j)*64 + lane)*8 + e] = bf16( W[(j*16 + (lane&15))*768 + kk*32 + (lane>>4)*8 + e] )
// so a wave's B-load for (kk,j) is one fully-contiguous 1-KB global_load_dwordx4.
__global__ void wpack_kernel(const float* __restrict__ w, unsigned short* __restrict__ wf) {
    const int t    = blockIdx.x * blockDim.x + threadIdx.x;   // 0..24575
    const int lane = t & 63;
    const int j    = (t >> 6) & 15;
    const int kk   = t >> 10;                                 // 0..23
    const int n    = j * 16 + (lane & 15);
    const int k    = kk * 32 + (lane >> 4) * 8;
    const float* src = w + (size_t)n * DIM + k;
    float4 v0 = *(const float4*)src;
    float4 v1 = *(const float4*)(src + 4);
    union { bf16x8 v; uint4 q; } o;
    o.v = pack_bf8(v0, v1);
    *(uint4*)(wf + (size_t)t * 8) = o.q;
}

// ---------------- kernel 1: barrier-free GEMM  proj[M,256] = A[M,768](fp32->bf16) x W^T --------
// Block = 4 waves x 32 rows = 128 rows; each wave computes 32x256 (acc[2][16]).
// A: direct global->VGPR in fragment layout (128 B/row per kk, read once).
// B: direct global->VGPR from pre-packed fragments (L1/L2-resident).
// ZERO __syncthreads in the K-loop; compiler pipelines loads against MFMA.
__global__ __launch_bounds__(256, 2) void gemm_kernel(const float* __restrict__ A,
                                                      const unsigned short* __restrict__ Bf,
                                                      unsigned short* __restrict__ Cb) {
    __shared__ unsigned short sC[4 * 32 * 256];   // 64 KB, epilogue transpose only

    const int tid  = threadIdx.x;
    const int w    = tid >> 6;
    const int lane = tid & 63;
    const int l15  = lane & 15;
    const int quad = lane >> 4;
    const int m0   = blockIdx.x * 128;

    f32x4 acc[2][16] = {};

    const float* a0 = A + (size_t)(m0 + w * 32 + l15) * DIM + quad * 8;   // i=0 row set
    const float* a1 = a0 + (size_t)16 * DIM;                               // i=1 row set
    const uint4* bp = (const uint4*)Bf + lane;                             // + (kk*16+j)*64

    #pragma unroll 2
    for (int kk = 0; kk < 24; ++kk) {
        const float4 r00 = *(const float4*)(a0 + kk * 32);
        const float4 r01 = *(const float4*)(a0 + kk * 32 + 4);
        const float4 r10 = *(const float4*)(a1 + kk * 32);
        const float4 r11 = *(const float4*)(a1 + kk * 32 + 4);
        const bf16x8 af0 = pack_bf8(r00, r01);
        const bf16x8 af1 = pack_bf8(r10, r11);
        #pragma unroll
        for (int j = 0; j < 16; ++j) {
            union { uint4 q; bf16x8 v; } b;
            b.q = bp[(kk * 16 + j) * 64];
            acc[0][j] = __builtin_amdgcn_mfma_f32_16x16x32_bf16(af0, b.v, acc[0][j], 0, 0, 0);
            acc[1][j] = __builtin_amdgcn_mfma_f32_16x16x32_bf16(af1, b.v, acc[1][j], 0, 0, 0);
        }
    }

    // ---- epilogue: per-wave LDS transpose -> 256-B-contiguous coalesced bf16 stores ----
    unsigned short* reg = sC + w * (32 * 256);
    #pragma unroll
    for (int i = 0; i < 2; ++i)
        #pragma unroll
        for (int j = 0; j < 16; ++j)
            #pragma unroll
            for (int rr = 0; rr < 4; ++rr)
                reg[(i * 16 + quad * 4 + rr) * 256 + j * 16 + l15] = f2bf(acc[i][j][rr]);
    __syncthreads();

    const int orow = tid >> 3;          // 0..31
    const int ou   = tid & 7;           // 8 lanes x 64 B = 512 B contiguous per row
    #pragma unroll
    for (int rb = 0; rb < 4; ++rb) {
        const int row = orow + rb * 32;                       // 0..127
        const unsigned short* src = sC + row * 256 + ou * 32; // row>>5 selects wave region
        unsigned short* dst = Cb + (size_t)(m0 + row) * NCOLS + ou * 32;
        #pragma unroll
        for (int q = 0; q < 4; ++q)
            *(uint4*)(dst + q * 8) = *(const uint4*)(src + q * 8);
    }
}

// ---------------- kernel 2: gather-mean, block per (batch, patch-row h) ----------------
// LDS: full cur row (32 KB) + dh 8..15 half of prev row (16 KB) = 48 KB.
__global__ __launch_bounds__(256) void gather_kernel(const unsigned short* __restrict__ proj,
                                                     float* __restrict__ out) {
    __shared__ unsigned short sCur[64 * 256];
    __shared__ unsigned short sPrevHi[64 * 128];

    const int blk = blockIdx.x;          // b*64 + h
    const int b   = blk >> 6;
    const int h   = blk & 63;
    const int tid = threadIdx.x;
    const unsigned short* base = proj + (size_t)b * (NPATCH * NCOLS);

    const uint4* gCur = (const uint4*)(base + (size_t)h * 64 * 256);
    #pragma unroll
    for (int p = 0; p < 8; ++p)
        ((uint4*)sCur)[tid + p * 256] = gCur[tid + p * 256];
    if (h > 0) {
        const uint4* gPrev = (const uint4*)(base + (size_t)(h - 1) * 64 * 256);
        #pragma unroll
        for (int p = 0; p < 4; ++p) {
            int i = tid + p * 256;       // patch = i>>4, 16B-unit = i&15 of hi half
            ((uint4*)sPrevHi)[i] = gPrev[(i >> 4) * 32 + 16 + (i & 15)];
        }
    }
    __syncthreads();

    const int r  = tid >> 5;             // output row in block: ph = 8h + r
    const int cg = tid & 31;             // 16 pixels: pw = cg*16 .. +15
    const int ph = h * 8 + r;
    const float inv_ch = (h == 0) ? 1.f : ((ph == 511) ? 0.1f : 0.5f);

    float res[16];
    #pragma unroll
    for (int j = 0; j < 16; ++j) {
        const int pw = cg * 16 + j;
        const int w1 = pw >> 3, dw = pw & 7;
        float v = bf2f(sCur[w1 * 256 + r * 16 + dw]);
        if (pw >= 8) v += bf2f(sCur[(w1 - 1) * 256 + r * 16 + dw + 8]);
        if (h > 0) {
            v += bf2f(sPrevHi[w1 * 128 + r * 16 + dw]);
            if (pw >= 8) v += bf2f(sPrevHi[(w1 - 1) * 128 + r * 16 + dw + 8]);
        }
        if (pw == 511) {                 // w-clamp extras: dw 8..15 of patch 63
            #pragma unroll
            for (int dwe = 8; dwe < 16; ++dwe) {
                v += bf2f(sCur[63 * 256 + r * 16 + dwe]);
                if (h > 0) v += bf2f(sPrevHi[63 * 128 + r * 16 + dwe]);
            }
        }
        if (ph == 511) {                 // h-clamp extras: dh 8..15 of cur row 63
            #pragma unroll 1
            for (int dh = 8; dh < 16; ++dh) {
                float e = bf2f(sCur[w1 * 256 + dh * 16 + dw]);
                if (pw >= 8) e += bf2f(sCur[(w1 - 1) * 256 + dh * 16 + dw + 8]);
                if (pw == 511) {
                    #pragma unroll
                    for (int dwe = 8; dwe < 16; ++dwe)
                        e += bf2f(sCur[63 * 256 + dh * 16 + dwe]);
                }
                v += e;
            }
        }
        const float inv_cw = (pw < 8) ? 1.f : ((pw == 511) ? 0.1f : 0.5f);
        res[j] = v * inv_ch * inv_cw;
    }

    float* orow = out + ((size_t)(b * 512 + ph)) * 512 + cg * 16;
    #pragma unroll
    for (int q = 0; q < 4; ++q)
        *(float4*)(orow + q * 4) = make_float4(res[4 * q], res[4 * q + 1], res[4 * q + 2], res[4 * q + 3]);
}

extern "C" void kernel_launch(void* const* d_in, const int* in_sizes, int n_in,
                              void* d_out, int out_size, void* d_ws, size_t ws_size,
                              hipStream_t stream) {
    const float* tgt    = (const float*)d_in[0];   // [16,4096,768] fp32
    const float* weight = (const float*)d_in[1];   // [16,16,768]  fp32
    float* out = (float*)d_out;                    // [16,512,512] fp32

    unsigned short* proj = (unsigned short*)d_ws;                                      // 32 MB bf16
    unsigned short* wf   = (unsigned short*)((char*)d_ws + (size_t)MROWS * NCOLS * 2); // +384 KB fragments

    wpack_kernel<<<96, 256, 0, stream>>>(weight, wf);               // 24576 threads
    gemm_kernel<<<MROWS / 128, 256, 0, stream>>>(tgt, wf, proj);    // 512 blocks
    gather_kernel<<<BATCH * 64, 256, 0, stream>>>(proj, out);       // 1024 blocks
}

// Round 6
// 323.049 us; speedup vs baseline: 1.3054x; 1.1519x over previous
//
#include <hip/hip_runtime.h>
#include <hip/hip_bf16.h>

// FieldDecoder: B=16, 64x64 tokens, DO=768, kernel 16x16, stride 8, field 512x512
#define DIM      768
#define NPATCH   4096
#define BATCH    16
#define MROWS    65536
#define NCOLS    256

typedef __attribute__((ext_vector_type(8))) short bf16x8;
typedef __attribute__((ext_vector_type(4))) float f32x4;

static __device__ __forceinline__ unsigned short f2bf(float f) {
    union { float f; unsigned int u; } v; v.f = f;
    unsigned int u = v.u;
    return (unsigned short)((u + 0x7FFFu + ((u >> 16) & 1u)) >> 16);
}
static __device__ __forceinline__ float bf2f(unsigned int u16) {
    union { unsigned int i; float f; } x; x.i = u16 << 16; return x.f;
}
static __device__ __forceinline__ bf16x8 pack_bf8(float4 a, float4 b) {
    union { bf16x8 v; unsigned int u[4]; } r;
    r.u[0] = (unsigned)f2bf(a.x) | ((unsigned)f2bf(a.y) << 16);
    r.u[1] = (unsigned)f2bf(a.z) | ((unsigned)f2bf(a.w) << 16);
    r.u[2] = (unsigned)f2bf(b.x) | ((unsigned)f2bf(b.y) << 16);
    r.u[3] = (unsigned)f2bf(b.z) | ((unsigned)f2bf(b.w) << 16);
    return r.v;
}

// ---------------- kernel 0: pack W into MFMA B-fragment order ----------------
// Bfrag[((kk*16 + j)*64 + lane)*8 + e] = bf16( W[(j*16 + (lane&15))*768 + kk*32 + (lane>>4)*8 + e] )
__global__ void wpack_kernel(const float* __restrict__ w, unsigned short* __restrict__ wf) {
    const int t    = blockIdx.x * blockDim.x + threadIdx.x;   // 0..24575
    const int lane = t & 63;
    const int j    = (t >> 6) & 15;
    const int kk   = t >> 10;                                 // 0..23
    const int n    = j * 16 + (lane & 15);
    const int k    = kk * 32 + (lane >> 4) * 8;
    const float* src = w + (size_t)n * DIM + k;
    float4 v0 = *(const float4*)src;
    float4 v1 = *(const float4*)(src + 4);
    union { bf16x8 v; uint4 q; } o;
    o.v = pack_bf8(v0, v1);
    *(uint4*)(wf + (size_t)t * 8) = o.q;
}

// ---------------- kernel 1: GEMM  proj[M,256] = A[M,768](fp32->bf16) x W^T ----------------
// Block = 4 waves x 32 rows = 128 rows. Wave computes 32x256 (acc[2][16]).
// B fragments staged per 128-K chunk into 64 KB LDS from L2 (12 barriers/block total);
// K-loop VMEM = 4 A-loads/kk only -> deep prefetch within chunk; B via conflict-free ds_read_b128.
__global__ __launch_bounds__(256, 2) void gemm_kernel(const float* __restrict__ A,
                                                      const unsigned short* __restrict__ Bf,
                                                      unsigned short* __restrict__ Cb) {
    __shared__ unsigned short smem[128 * 256];   // 64 KB: B-chunk staging | epilogue transpose

    const int tid  = threadIdx.x;
    const int w    = tid >> 6;
    const int lane = tid & 63;
    const int l15  = lane & 15;
    const int quad = lane >> 4;
    const int m0   = blockIdx.x * 128;

    f32x4 acc[2][16] = {};

    const float* a0 = A + (size_t)(m0 + w * 32 + l15) * DIM + quad * 8;
    const float* a1 = a0 + (size_t)16 * DIM;

    for (int c = 0; c < 6; ++c) {
        __syncthreads();                           // previous chunk's ds_reads complete
        {   // stage B chunk c: 4096 uint4 (64 KB), fully contiguous, L2-resident
            const uint4* src = (const uint4*)Bf + c * 4096 + tid;
            uint4* dst = (uint4*)smem + tid;
            #pragma unroll 4
            for (int s = 0; s < 16; ++s)
                dst[s * 256] = src[s * 256];
        }
        __syncthreads();

        #pragma unroll
        for (int kk = 0; kk < 4; ++kk) {
            const int kg = c * 4 + kk;
            const float4 r00 = *(const float4*)(a0 + kg * 32);
            const float4 r01 = *(const float4*)(a0 + kg * 32 + 4);
            const float4 r10 = *(const float4*)(a1 + kg * 32);
            const float4 r11 = *(const float4*)(a1 + kg * 32 + 4);
            const bf16x8 af0 = pack_bf8(r00, r01);
            const bf16x8 af1 = pack_bf8(r10, r11);
            #pragma unroll
            for (int j = 0; j < 16; ++j) {
                const bf16x8 b = *(const bf16x8*)(smem + ((kk * 16 + j) * 64 + lane) * 8);
                acc[0][j] = __builtin_amdgcn_mfma_f32_16x16x32_bf16(af0, b, acc[0][j], 0, 0, 0);
                acc[1][j] = __builtin_amdgcn_mfma_f32_16x16x32_bf16(af1, b, acc[1][j], 0, 0, 0);
            }
        }
    }

    // ---- epilogue: LDS transpose -> 512 B/row coalesced bf16 stores ----
    __syncthreads();                               // all B reads done; reuse smem
    #pragma unroll
    for (int i = 0; i < 2; ++i)
        #pragma unroll
        for (int j = 0; j < 16; ++j)
            #pragma unroll
            for (int rr = 0; rr < 4; ++rr)
                smem[(w * 32 + i * 16 + quad * 4 + rr) * 256 + j * 16 + l15] = f2bf(acc[i][j][rr]);
    __syncthreads();

    const int orow = tid >> 3;          // 0..31
    const int ou   = tid & 7;           // 8 lanes x 64 B = 512 B per row
    #pragma unroll
    for (int rb = 0; rb < 4; ++rb) {
        const int row = orow + rb * 32;
        const unsigned short* src = smem + row * 256 + ou * 32;
        unsigned short* dst = Cb + (size_t)(m0 + row) * NCOLS + ou * 32;
        #pragma unroll
        for (int q = 0; q < 4; ++q)
            *(uint4*)(dst + q * 8) = *(const uint4*)(src + q * 8);
    }
}

// ---------------- kernel 2: gather-mean, block per (batch, patch-row h) ----------------
// LDS staging with bank-rotated padded strides; inner compute via ds_read_b128 (4 per 8-pixel task).
#define CSTRG 280   // sCur row stride (shorts): 560 B -> lane bank-start 12*wg mod 32 (full spread)
#define PSTRG 152   // sPrevHi row stride: 304 B -> same rotation
__global__ __launch_bounds__(256, 2) void gather_kernel(const unsigned short* __restrict__ proj,
                                                        float* __restrict__ out) {
    __shared__ unsigned short sCur[64 * CSTRG];     // 35840 B
    __shared__ unsigned short sPrevHi[64 * PSTRG];  // 19456 B

    const int blk = blockIdx.x;          // b*64 + h
    const int b   = blk >> 6;
    const int h   = blk & 63;
    const int tid = threadIdx.x;
    const unsigned short* base = proj + (size_t)b * (NPATCH * NCOLS);

    const uint4* gCur = (const uint4*)(base + (size_t)h * 64 * 256);
    #pragma unroll
    for (int p = 0; p < 8; ++p) {
        const int i = tid + p * 256;     // 2048 uint4: patch = i>>5, q = i&31
        *(uint4*)(sCur + (i >> 5) * CSTRG + (i & 31) * 8) = gCur[i];
    }
    if (h > 0) {
        const uint4* gPrev = (const uint4*)(base + (size_t)(h - 1) * 64 * 256);
        #pragma unroll
        for (int p = 0; p < 4; ++p) {
            const int i = tid + p * 256; // 1024 uint4: patch = i>>4, hi-half q = i&15
            *(uint4*)(sPrevHi + (i >> 4) * PSTRG + (i & 15) * 8) = gPrev[(i >> 4) * 32 + 16 + (i & 15)];
        }
    }
    __syncthreads();

    const float fch_base = (h == 0) ? 1.f : 0.5f;

    #pragma unroll
    for (int t = 0; t < 2; ++t) {
        const int task = tid + t * 256;  // r = task>>6 (wave-uniform), wg = lane
        const int r  = task >> 6;
        const int wg = task & 63;
        const int ph = h * 8 + r;

        float s[8] = {0.f, 0.f, 0.f, 0.f, 0.f, 0.f, 0.f, 0.f};
        auto addq = [&](uint4 v) {
            const unsigned int u[4] = {v.x, v.y, v.z, v.w};
            #pragma unroll
            for (int q = 0; q < 4; ++q) {
                s[2 * q]     += bf2f(u[q] & 0xFFFFu);
                s[2 * q + 1] += bf2f(u[q] >> 16);
            }
        };
        auto sumq = [&](uint4 v) -> float {
            const unsigned int u[4] = {v.x, v.y, v.z, v.w};
            float e = 0.f;
            #pragma unroll
            for (int q = 0; q < 4; ++q) e += bf2f(u[q] & 0xFFFFu) + bf2f(u[q] >> 16);
            return e;
        };

        addq(*(const uint4*)(sCur + wg * CSTRG + r * 16));                       // cur(h,wg) dw 0..7
        if (wg > 0) addq(*(const uint4*)(sCur + (wg - 1) * CSTRG + r * 16 + 8)); // cur(h,wg-1) dw 8..15
        if (h > 0) {
            addq(*(const uint4*)(sPrevHi + wg * PSTRG + r * 16));                // prev dh=r+8
            if (wg > 0) addq(*(const uint4*)(sPrevHi + (wg - 1) * PSTRG + r * 16 + 8));
        }
        if (wg == 63) {                   // w-clamp extras -> pixel 511 only
            s[7] += sumq(*(const uint4*)(sCur + 63 * CSTRG + r * 16 + 8));
            if (h > 0) s[7] += sumq(*(const uint4*)(sPrevHi + 63 * PSTRG + r * 16 + 8));
        }
        float fch = fch_base;
        if (ph == 511) {                  // h-clamp extras: dh 8..15 of cur patch-row 63
            fch = 0.1f;
            #pragma unroll 1
            for (int dh = 8; dh < 16; ++dh) {
                addq(*(const uint4*)(sCur + wg * CSTRG + dh * 16));
                if (wg > 0) addq(*(const uint4*)(sCur + (wg - 1) * CSTRG + dh * 16 + 8));
                if (wg == 63) s[7] += sumq(*(const uint4*)(sCur + 63 * CSTRG + dh * 16 + 8));
            }
        }

        const float fcw = (wg == 0) ? 1.f : 0.5f;
        float f7 = fcw;
        if (wg == 63) f7 = 0.1f;
        float* orow = out + ((size_t)(b * 512 + ph)) * 512 + wg * 8;
        *(float4*)orow       = make_float4(s[0] * fch * fcw, s[1] * fch * fcw,
                                           s[2] * fch * fcw, s[3] * fch * fcw);
        *(float4*)(orow + 4) = make_float4(s[4] * fch * fcw, s[5] * fch * fcw,
                                           s[6] * fch * fcw, s[7] * fch * f7);
    }
}

extern "C" void kernel_launch(void* const* d_in, const int* in_sizes, int n_in,
                              void* d_out, int out_size, void* d_ws, size_t ws_size,
                              hipStream_t stream) {
    const float* tgt    = (const float*)d_in[0];   // [16,4096,768] fp32
    const float* weight = (const float*)d_in[1];   // [16,16,768]  fp32
    float* out = (float*)d_out;                    // [16,512,512] fp32

    unsigned short* proj = (unsigned short*)d_ws;                                      // 32 MB bf16
    unsigned short* wf   = (unsigned short*)((char*)d_ws + (size_t)MROWS * NCOLS * 2); // +384 KB fragments

    wpack_kernel<<<96, 256, 0, stream>>>(weight, wf);               // 24576 threads
    gemm_kernel<<<MROWS / 128, 256, 0, stream>>>(tgt, wf, proj);    // 512 blocks
    gather_kernel<<<BATCH * 64, 256, 0, stream>>>(proj, out);       // 1024 blocks
}